// Round 2
// baseline (920.444 us; speedup 1.0000x reference)
//
#include <hip/hip_runtime.h>
#include <hip/hip_bf16.h>
#include <math.h>

#define BB 16
#define T_EN 1024
#define C_INN 512
#define C_H 256
#define KSZ 5
#define PADW 2

// ---------------- conv-as-GEMM (fp32) ----------------
// out[b,t,co] = relu( sum_{kk,ci} x[b,t+kk-2,ci] * wT[kk,ci,co] + bias[co] )
#define BM 128
#define BN 64
#define BKC 32

__global__ __launch_bounds__(256) void conv_gemm(
    const float* __restrict__ x,    // [B, T_EN, Cin]
    const float* __restrict__ wT,   // [KSZ, Cin, C_H]
    const float* __restrict__ bias, // [C_H]
    float* __restrict__ y,          // [B, T_EN, C_H]
    int Cin)
{
    __shared__ float Asm[BKC][BM + 4];   // +4 pad keeps 16B alignment, reduces conflicts
    __shared__ float Bsm[BKC][BN];

    const int t0 = blockIdx.x * BM;
    const int n0 = blockIdx.y * BN;
    const int b  = blockIdx.z;
    const int tid = threadIdx.x;
    const int tm = tid & 15;   // m-group (x4, two 64-row halves)
    const int tn = tid >> 4;   // n-group (x4)

    float acc[8][4];
#pragma unroll
    for (int i = 0; i < 8; ++i)
#pragma unroll
        for (int j = 0; j < 4; ++j) acc[i][j] = 0.f;

    const float* xb = x + (size_t)b * T_EN * Cin;
    const int cq = tid & 7;    // A-load: float4 within 32-ci chunk
    const int rr = tid >> 3;   // A-load: row 0..31
    const int n4 = tid & 15;   // B-load: float4 within 64 co
    const int kr = tid >> 4;   // B-load: ci row 0..15

    for (int kk = 0; kk < KSZ; ++kk) {
        const float* wk = wT + (size_t)kk * Cin * C_H;
        for (int c0 = 0; c0 < Cin; c0 += BKC) {
            __syncthreads();
            // ---- stage A (im2col slice) transposed: Asm[ci][m] ----
#pragma unroll
            for (int p = 0; p < 4; ++p) {
                int m = rr + 32 * p;
                int t = t0 + m + kk - PADW;
                float4 v = make_float4(0.f, 0.f, 0.f, 0.f);
                if ((unsigned)t < (unsigned)T_EN)
                    v = *(const float4*)(xb + (size_t)t * Cin + (c0 + cq * 4));
                Asm[cq * 4 + 0][m] = v.x;
                Asm[cq * 4 + 1][m] = v.y;
                Asm[cq * 4 + 2][m] = v.z;
                Asm[cq * 4 + 3][m] = v.w;
            }
            // ---- stage B (weights): Bsm[ci][co] ----
#pragma unroll
            for (int p = 0; p < 2; ++p) {
                int krow = kr + 16 * p;
                float4 v = *(const float4*)(wk + (size_t)(c0 + krow) * C_H + (n0 + n4 * 4));
                *(float4*)&Bsm[krow][n4 * 4] = v;
            }
            __syncthreads();
            // ---- inner product ----
#pragma unroll
            for (int kki = 0; kki < BKC; ++kki) {
                const float4 a0 = *(const float4*)&Asm[kki][tm * 4];
                const float4 a1 = *(const float4*)&Asm[kki][64 + tm * 4];
                const float4 b0 = *(const float4*)&Bsm[kki][tn * 4];
                float av[8] = {a0.x, a0.y, a0.z, a0.w, a1.x, a1.y, a1.z, a1.w};
                float bv[4] = {b0.x, b0.y, b0.z, b0.w};
#pragma unroll
                for (int i = 0; i < 8; ++i)
#pragma unroll
                    for (int j = 0; j < 4; ++j)
                        acc[i][j] = fmaf(av[i], bv[j], acc[i][j]);
            }
        }
    }
    // ---- epilogue: bias + relu ----
    const float4 bb = *(const float4*)(bias + n0 + tn * 4);
#pragma unroll
    for (int i = 0; i < 8; ++i) {
        int m = ((i >> 2) * 64) + tm * 4 + (i & 3);
        float4 o;
        o.x = fmaxf(acc[i][0] + bb.x, 0.f);
        o.y = fmaxf(acc[i][1] + bb.y, 0.f);
        o.z = fmaxf(acc[i][2] + bb.z, 0.f);
        o.w = fmaxf(acc[i][3] + bb.w, 0.f);
        *(float4*)(y + ((size_t)b * T_EN + (t0 + m)) * C_H + n0 + tn * 4) = o;
    }
}

// ---------------- weight transpose: w[co][ci][k] -> wT[k][ci][co] ----------------
__global__ void transpose_w(const float* __restrict__ w, float* __restrict__ wT, int Cin)
{
    int co = threadIdx.x;          // 256
    int ci = blockIdx.y;
    int kk = blockIdx.z;
    wT[((size_t)kk * Cin + ci) * C_H + co] = w[((size_t)co * Cin + ci) * KSZ + kk];
}

// ---------------- LayerNorm (in-place), input already relu'd ----------------
__global__ __launch_bounds__(256) void ln_inplace(
    float* __restrict__ y, const float* __restrict__ g, const float* __restrict__ beta)
{
    int row  = blockIdx.x * 4 + (threadIdx.x >> 6);
    int lane = threadIdx.x & 63;
    float* p = y + (size_t)row * C_H;
    float4 v = *(float4*)(p + lane * 4);
    float s = v.x + v.y + v.z + v.w;
    float q = v.x * v.x + v.y * v.y + v.z * v.z + v.w * v.w;
#pragma unroll
    for (int d = 32; d >= 1; d >>= 1) {
        s += __shfl_xor(s, d);
        q += __shfl_xor(q, d);
    }
    float mean = s * (1.f / 256.f);
    float var  = q * (1.f / 256.f) - mean * mean;
    float inv  = rsqrtf(var + 1e-5f);
    float4 gg = *(const float4*)(g + lane * 4);
    float4 bb = *(const float4*)(beta + lane * 4);
    v.x = (v.x - mean) * inv * gg.x + bb.x;
    v.y = (v.y - mean) * inv * gg.y + bb.y;
    v.z = (v.z - mean) * inv * gg.z + bb.z;
    v.w = (v.w - mean) * inv * gg.w + bb.w;
    *(float4*)(p + lane * 4) = v;
}

// ---------------- linear head + mask (mask == (dur==0)) ----------------
__global__ __launch_bounds__(256) void linear_mask(
    const float* __restrict__ h, const float* __restrict__ lw, const float* __restrict__ lb,
    const float* __restrict__ dur, float* __restrict__ out2)
{
    int row  = blockIdx.x * 4 + (threadIdx.x >> 6);
    int lane = threadIdx.x & 63;
    float4 v = *(const float4*)(h + (size_t)row * C_H + lane * 4);
    float4 w = *(const float4*)(lw + lane * 4);
    float s = v.x * w.x + v.y * w.y + v.z * w.z + v.w * w.w;
#pragma unroll
    for (int d = 32; d >= 1; d >>= 1) s += __shfl_xor(s, d);
    if (lane == 0) {
        float o = s + lb[0];
        if (dur[row] == 0.f) o = 0.f;
        out2[row] = o;
    }
}

// ---------------- per-batch inclusive scan of durations ----------------
__global__ __launch_bounds__(256) void scan_dur(const float* __restrict__ dur, float* __restrict__ cum)
{
    int b = blockIdx.x;
    const float* d = dur + (size_t)b * T_EN;
    float* c = cum + (size_t)b * T_EN;
    int tid = threadIdx.x, lane = tid & 63, wid = tid >> 6;
    float v0 = d[tid * 4 + 0], v1 = d[tid * 4 + 1], v2 = d[tid * 4 + 2], v3 = d[tid * 4 + 3];
    float p0 = v0, p1 = p0 + v1, p2 = p1 + v2, p3 = p2 + v3;
    float s = p3;
    float x = s;
#pragma unroll
    for (int dl = 1; dl < 64; dl <<= 1) {
        float o = __shfl_up(x, dl, 64);
        if (lane >= dl) x += o;
    }
    __shared__ float wsum[4];
    if (lane == 63) wsum[wid] = x;
    __syncthreads();
    float off = 0.f;
    for (int w = 0; w < wid; ++w) off += wsum[w];
    float excl = off + x - s;
    c[tid * 4 + 0] = excl + p0;
    c[tid * 4 + 1] = excl + p1;
    c[tid * 4 + 2] = excl + p2;
    c[tid * 4 + 3] = excl + p3;
}

// ---------------- scatter: ty->tx map + ones into attn^T ----------------
__global__ __launch_bounds__(256) void scatter_ones(
    const float* __restrict__ cum, int* __restrict__ map, float* __restrict__ out4, int tde)
{
    int idx = blockIdx.x * 256 + threadIdx.x;   // b*T_EN + tx
    int b = idx >> 10, tx = idx & 1023;
    float c1f = cum[idx];
    float c0f = tx ? cum[idx - 1] : 0.f;
    int c0 = (int)c0f, c1 = (int)c1f;
    float* o4 = out4 + (size_t)b * tde * T_EN + tx;
    int* mp = map + (size_t)b * tde;
    for (int ty = c0; ty < c1; ++ty) {
        mp[ty] = tx;
        o4[(size_t)ty * T_EN] = 1.f;
    }
}

// ---------------- gather: out3[b,c,ty] = enc[b, map[ty], c] ----------------
__global__ __launch_bounds__(256) void gather_out3(
    const float* __restrict__ enc, const float* __restrict__ cum,
    const int* __restrict__ map, float* __restrict__ out3, int tde)
{
    int bc = blockIdx.y;            // b*C_IN + c
    int b = bc >> 9, c = bc & 511;
    int ty = blockIdx.x * 256 + threadIdx.x;
    if (ty >= tde) return;
    int mel = (int)cum[(size_t)b * T_EN + T_EN - 1];
    float val = 0.f;
    if (ty < mel) {
        int tx = map[(size_t)b * tde + ty];
        val = enc[((size_t)b * T_EN + tx) * C_INN + c];
    }
    out3[(size_t)bc * tde + ty] = val;
}

extern "C" void kernel_launch(void* const* d_in, const int* in_sizes, int n_in,
                              void* d_out, int out_size, void* d_ws, size_t ws_size,
                              hipStream_t stream)
{
    const float* enc      = (const float*)d_in[0];
    const float* enc_res  = (const float*)d_in[1];
    const float* dur      = (const float*)d_in[2];
    const float* c1w      = (const float*)d_in[3];
    const float* c1b      = (const float*)d_in[4];
    const float* g1       = (const float*)d_in[5];
    const float* b1       = (const float*)d_in[6];
    const float* c2w      = (const float*)d_in[7];
    const float* c2b      = (const float*)d_in[8];
    const float* g2       = (const float*)d_in[9];
    const float* b2       = (const float*)d_in[10];
    const float* lw       = (const float*)d_in[11];
    const float* lb       = (const float*)d_in[12];

    // out_size = B*T_EN + T_DE * B*(2*T_EN + C_IN)
    const int tde = (out_size - BB * T_EN) / (BB * (2 * T_EN + C_INN));

    float* out1 = (float*)d_out;                                   // [B,T_EN,T_DE] == 0
    float* out2 = out1 + (size_t)BB * T_EN * tde;                  // [B,T_EN]
    float* out3 = out2 + (size_t)BB * T_EN;                        // [B,C_IN,T_DE]
    float* out4 = out3 + (size_t)BB * C_INN * tde;                 // [B,T_DE,T_EN]

    float* ws    = (float*)d_ws;
    float* w1T   = ws;                         // 5*512*256
    float* w2T   = w1T + (size_t)KSZ * C_INN * C_H;
    float* ybuf1 = w2T + (size_t)KSZ * C_H * C_H;
    float* ybuf2 = ybuf1 + (size_t)BB * T_EN * C_H;
    float* cum   = ybuf2 + (size_t)BB * T_EN * C_H;
    int*   map   = (int*)(cum + (size_t)BB * T_EN);

    // zero-fill the two alignment outputs
    hipMemsetAsync(out1, 0, (size_t)BB * T_EN * tde * sizeof(float), stream);
    hipMemsetAsync(out4, 0, (size_t)BB * tde * T_EN * sizeof(float), stream);

    // weight transposes
    transpose_w<<<dim3(1, C_INN, KSZ), 256, 0, stream>>>(c1w, w1T, C_INN);
    transpose_w<<<dim3(1, C_H,  KSZ), 256, 0, stream>>>(c2w, w2T, C_H);

    // variance predictor
    conv_gemm<<<dim3(T_EN / BM, C_H / BN, BB), 256, 0, stream>>>(enc_res, w1T, c1b, ybuf1, C_INN);
    ln_inplace<<<dim3(BB * T_EN / 4), 256, 0, stream>>>(ybuf1, g1, b1);
    conv_gemm<<<dim3(T_EN / BM, C_H / BN, BB), 256, 0, stream>>>(ybuf1, w2T, c2b, ybuf2, C_H);
    ln_inplace<<<dim3(BB * T_EN / 4), 256, 0, stream>>>(ybuf2, g2, b2);
    linear_mask<<<dim3(BB * T_EN / 4), 256, 0, stream>>>(ybuf2, lw, lb, dur, out2);

    // alignment path (exact integer durations)
    scan_dur<<<dim3(BB), 256, 0, stream>>>(dur, cum);
    scatter_ones<<<dim3(BB * T_EN / 256), 256, 0, stream>>>(cum, map, out4, tde);
    gather_out3<<<dim3((tde + 255) / 256, BB * C_INN), 256, 0, stream>>>(enc, cum, map, out3, tde);
}

// Round 3
// 601.579 us; speedup vs baseline: 1.5300x; 1.5300x over previous
//
#include <hip/hip_runtime.h>
#include <hip/hip_bf16.h>
#include <math.h>

#define BB 16
#define T_EN 1024
#define TPAD 1028
#define C_INN 512
#define C_H 256
#define KSZ 5

typedef __bf16 bf16x8 __attribute__((ext_vector_type(8)));
typedef float  f32x4  __attribute__((ext_vector_type(4)));

__device__ __forceinline__ unsigned short f2bf(float x) {
    __hip_bfloat16 h = __float2bfloat16(x);
    return *reinterpret_cast<unsigned short*>(&h);
}
__device__ __forceinline__ float bf2f(unsigned short u) {
    __hip_bfloat16 h = *reinterpret_cast<__hip_bfloat16*>(&u);
    return __bfloat162float(h);
}
__device__ __forceinline__ void split_bf(float x, unsigned short& hi, unsigned short& lo) {
    unsigned short h = f2bf(x);
    hi = h;
    lo = f2bf(x - bf2f(h));
}

__device__ __forceinline__ void gl_lds16(const void* g, void* l) {
    __builtin_amdgcn_global_load_lds(
        (const __attribute__((address_space(1))) unsigned int*)g,
        (__attribute__((address_space(3))) unsigned int*)l, 16, 0, 0);
}

// ============ MFMA conv-as-GEMM, split-bf16 (hi/lo) ============
// out[b,t,co] = relu( sum_{kk,ci} x[b,t+kk-2,ci]*w[kk,ci,co] + bias[co] )
// x given as padded hi/lo bf16 [B][TPAD][CIN] (rows 0,1,TPAD-2,TPAD-1 are zero)
// w given as hi/lo bf16 in [KSZ][C_H][CIN] layout (B^T style: [n][k])
template<int CIN>
__global__ __launch_bounds__(256) void conv_mfma(
    const unsigned short* __restrict__ xhi, const unsigned short* __restrict__ xlo,
    const unsigned short* __restrict__ whi, const unsigned short* __restrict__ wlo,
    const float* __restrict__ bias, float* __restrict__ y)
{
    constexpr int NS = KSZ * CIN / 32;
    __shared__ char smem[65536];   // 2 buffers x (Ahi 8K, Alo 8K, Bhi 8K, Blo 8K)

    const int t0 = blockIdx.x * 128, n0 = blockIdx.y * 128, b = blockIdx.z;
    const int tid = threadIdx.x, lane = tid & 63;
    const int wr = (tid >> 6) >> 1, wc = (tid >> 6) & 1;
    const int l15 = lane & 15, k8 = lane >> 4;

    f32x4 acc[4][4];
#pragma unroll
    for (int i = 0; i < 4; ++i)
#pragma unroll
        for (int j = 0; j < 4; ++j) acc[i][j] = (f32x4){0.f, 0.f, 0.f, 0.f};

    auto stage = [&](int s, int bufi) {
        const int kk = s / (CIN / 32);
        const int ci0 = (s % (CIN / 32)) * 32;
        char* bufA_hi = smem + bufi * 32768;
        char* bufA_lo = bufA_hi + 8192;
        char* bufB_hi = bufA_hi + 16384;
        char* bufB_lo = bufA_hi + 24576;
        const int tp0 = t0 + kk;   // padded row base (t = tp-2 => t0+m+kk-2)
#pragma unroll
        for (int p = 0; p < 2; ++p) {
            const int row = p * 64 + (tid >> 2);      // 0..127 (tile-local)
            const int k8l = tid & 3;
            const int k8s = k8l ^ ((row ^ (row >> 2)) & 3);   // source pre-swizzle
            const int lb = (p * 256 + (tid & 192)) * 16;      // wave-uniform LDS byte base
            const size_t ga = (size_t)(b * TPAD + tp0 + row) * CIN + ci0 + k8s * 8;
            gl_lds16(xhi + ga, bufA_hi + lb);
            gl_lds16(xlo + ga, bufA_lo + lb);
            const size_t gb = (size_t)(kk * C_H + n0 + row) * CIN + ci0 + k8s * 8;
            gl_lds16(whi + gb, bufB_hi + lb);
            gl_lds16(wlo + gb, bufB_lo + lb);
        }
    };

    auto compute = [&](int bufi) {
        const char* A_hi = smem + bufi * 32768;
        const char* A_lo = A_hi + 8192;
        const char* B_hi = A_hi + 16384;
        const char* B_lo = A_hi + 24576;
        bf16x8 ah[4], al[4], bh[4], bl[4];
#pragma unroll
        for (int mf = 0; mf < 4; ++mf) {
            const int r = wr * 64 + mf * 16 + l15;
            const int off = r * 64 + ((k8 ^ ((r ^ (r >> 2)) & 3)) * 16);
            ah[mf] = *(const bf16x8*)(A_hi + off);
            al[mf] = *(const bf16x8*)(A_lo + off);
        }
#pragma unroll
        for (int nf = 0; nf < 4; ++nf) {
            const int r = wc * 64 + nf * 16 + l15;
            const int off = r * 64 + ((k8 ^ ((r ^ (r >> 2)) & 3)) * 16);
            bh[nf] = *(const bf16x8*)(B_hi + off);
            bl[nf] = *(const bf16x8*)(B_lo + off);
        }
#pragma unroll
        for (int mf = 0; mf < 4; ++mf)
#pragma unroll
            for (int nf = 0; nf < 4; ++nf)
                acc[mf][nf] = __builtin_amdgcn_mfma_f32_16x16x32_bf16(ah[mf], bh[nf], acc[mf][nf], 0, 0, 0);
#pragma unroll
        for (int mf = 0; mf < 4; ++mf)
#pragma unroll
            for (int nf = 0; nf < 4; ++nf)
                acc[mf][nf] = __builtin_amdgcn_mfma_f32_16x16x32_bf16(ah[mf], bl[nf], acc[mf][nf], 0, 0, 0);
#pragma unroll
        for (int mf = 0; mf < 4; ++mf)
#pragma unroll
            for (int nf = 0; nf < 4; ++nf)
                acc[mf][nf] = __builtin_amdgcn_mfma_f32_16x16x32_bf16(al[mf], bh[nf], acc[mf][nf], 0, 0, 0);
    };

    stage(0, 0);
    __syncthreads();
    for (int s = 0; s < NS; ++s) {
        if (s + 1 < NS) stage(s + 1, (s + 1) & 1);
        compute(s & 1);
        __syncthreads();
    }

    // epilogue: bias + relu, C layout col=lane&15, row=(lane>>4)*4+j
    float bv[4];
#pragma unroll
    for (int nf = 0; nf < 4; ++nf) bv[nf] = bias[n0 + wc * 64 + nf * 16 + l15];
#pragma unroll
    for (int mf = 0; mf < 4; ++mf) {
        const int rbase = t0 + wr * 64 + mf * 16 + k8 * 4;
#pragma unroll
        for (int nf = 0; nf < 4; ++nf) {
            const int col = n0 + wc * 64 + nf * 16 + l15;
            f32x4 v = acc[mf][nf];
#pragma unroll
            for (int j = 0; j < 4; ++j)
                y[((size_t)(b * T_EN) + rbase + j) * C_H + col] = fmaxf(v[j] + bv[nf], 0.f);
        }
    }
}

// ============ fp32 -> padded hi/lo bf16 (encoder_output_res) ============
__global__ __launch_bounds__(256) void cvt_x(
    const float* __restrict__ src, unsigned short* __restrict__ hi, unsigned short* __restrict__ lo)
{
    const size_t i4 = (size_t)blockIdx.x * 256 + threadIdx.x;  // one float4
    const int c4 = (int)(i4 % (C_INN / 4));
    const int r  = (int)((i4 / (C_INN / 4)) % TPAD);
    const int b  = (int)(i4 / ((size_t)(C_INN / 4) * TPAD));
    const size_t dst = ((size_t)(b * TPAD + r)) * C_INN + c4 * 4;
    ushort4 h = {0, 0, 0, 0}, l = {0, 0, 0, 0};
    if (r >= 2 && r < TPAD - 2) {
        float4 v = *(const float4*)(src + ((size_t)(b * T_EN + r - 2)) * C_INN + c4 * 4);
        split_bf(v.x, h.x, l.x); split_bf(v.y, h.y, l.y);
        split_bf(v.z, h.z, l.z); split_bf(v.w, h.w, l.w);
    }
    *(ushort4*)(hi + dst) = h;
    *(ushort4*)(lo + dst) = l;
}

// ============ weights [C_H][CIN][KSZ] fp32 -> [KSZ][C_H][CIN] hi/lo bf16 ============
__global__ __launch_bounds__(256) void cvt_w(
    const float* __restrict__ w, unsigned short* __restrict__ whi, unsigned short* __restrict__ wlo, int CIN)
{
    const int idx = blockIdx.x * 256 + threadIdx.x;   // co*CIN + ci
    const int co = idx / CIN, ci = idx % CIN;
    const float* ps = w + ((size_t)co * CIN + ci) * KSZ;
#pragma unroll
    for (int kk = 0; kk < KSZ; ++kk) {
        unsigned short h, l;
        split_bf(ps[kk], h, l);
        const size_t d = ((size_t)kk * C_H + co) * CIN + ci;
        whi[d] = h; wlo[d] = l;
    }
}

// ============ LN1: fp32 conv1 out -> padded hi/lo bf16 [B][TPAD][C_H] ============
__global__ __launch_bounds__(256) void ln1_pad(
    const float* __restrict__ y1, const float* __restrict__ g, const float* __restrict__ be,
    unsigned short* __restrict__ ohi, unsigned short* __restrict__ olo)
{
    const int rp = blockIdx.x * 4 + (threadIdx.x >> 6);   // over B*TPAD rows
    const int lane = threadIdx.x & 63;
    const int b = rp / TPAD, r = rp % TPAD;
    const size_t dst = (size_t)rp * C_H + lane * 4;
    if (r < 2 || r >= TPAD - 2) {
        ushort4 z = {0, 0, 0, 0};
        *(ushort4*)(ohi + dst) = z;
        *(ushort4*)(olo + dst) = z;
        return;
    }
    float4 v = *(const float4*)(y1 + ((size_t)(b * T_EN + r - 2)) * C_H + lane * 4);
    float s = v.x + v.y + v.z + v.w;
    float q = v.x * v.x + v.y * v.y + v.z * v.z + v.w * v.w;
#pragma unroll
    for (int d = 32; d >= 1; d >>= 1) { s += __shfl_xor(s, d); q += __shfl_xor(q, d); }
    const float mean = s * (1.f / 256.f);
    const float var  = q * (1.f / 256.f) - mean * mean;
    const float inv  = rsqrtf(var + 1e-5f);
    const float4 gg = *(const float4*)(g + lane * 4);
    const float4 bb = *(const float4*)(be + lane * 4);
    float o0 = (v.x - mean) * inv * gg.x + bb.x;
    float o1 = (v.y - mean) * inv * gg.y + bb.y;
    float o2 = (v.z - mean) * inv * gg.z + bb.z;
    float o3 = (v.w - mean) * inv * gg.w + bb.w;
    ushort4 h, l;
    split_bf(o0, h.x, l.x); split_bf(o1, h.y, l.y);
    split_bf(o2, h.z, l.z); split_bf(o3, h.w, l.w);
    *(ushort4*)(ohi + dst) = h;
    *(ushort4*)(olo + dst) = l;
}

// ============ LN2 + linear head + duration mask fused ============
__global__ __launch_bounds__(256) void ln2_linear(
    const float* __restrict__ y2, const float* __restrict__ g, const float* __restrict__ be,
    const float* __restrict__ lw, const float* __restrict__ lb,
    const float* __restrict__ dur, float* __restrict__ out2)
{
    const int row = blockIdx.x * 4 + (threadIdx.x >> 6);
    const int lane = threadIdx.x & 63;
    float4 v = *(const float4*)(y2 + (size_t)row * C_H + lane * 4);
    float s = v.x + v.y + v.z + v.w;
    float q = v.x * v.x + v.y * v.y + v.z * v.z + v.w * v.w;
#pragma unroll
    for (int d = 32; d >= 1; d >>= 1) { s += __shfl_xor(s, d); q += __shfl_xor(q, d); }
    const float mean = s * (1.f / 256.f);
    const float var  = q * (1.f / 256.f) - mean * mean;
    const float inv  = rsqrtf(var + 1e-5f);
    const float4 gg = *(const float4*)(g + lane * 4);
    const float4 bb = *(const float4*)(be + lane * 4);
    const float4 w  = *(const float4*)(lw + lane * 4);
    float t0 = (v.x - mean) * inv * gg.x + bb.x;
    float t1 = (v.y - mean) * inv * gg.y + bb.y;
    float t2 = (v.z - mean) * inv * gg.z + bb.z;
    float t3 = (v.w - mean) * inv * gg.w + bb.w;
    float acc = t0 * w.x + t1 * w.y + t2 * w.z + t3 * w.w;
#pragma unroll
    for (int d = 32; d >= 1; d >>= 1) acc += __shfl_xor(acc, d);
    if (lane == 0) {
        float o = acc + lb[0];
        if (dur[row] == 0.f) o = 0.f;
        out2[row] = o;
    }
}

// ============ per-batch inclusive scan of durations ============
__global__ __launch_bounds__(256) void scan_dur(const float* __restrict__ dur, float* __restrict__ cum)
{
    const int b = blockIdx.x;
    const float* d = dur + (size_t)b * T_EN;
    float* c = cum + (size_t)b * T_EN;
    const int tid = threadIdx.x, lane = tid & 63, wid = tid >> 6;
    float v0 = d[tid * 4 + 0], v1 = d[tid * 4 + 1], v2 = d[tid * 4 + 2], v3 = d[tid * 4 + 3];
    float p0 = v0, p1 = p0 + v1, p2 = p1 + v2, p3 = p2 + v3;
    float s = p3, x = s;
#pragma unroll
    for (int dl = 1; dl < 64; dl <<= 1) {
        float o = __shfl_up(x, dl, 64);
        if (lane >= dl) x += o;
    }
    __shared__ float wsum[4];
    if (lane == 63) wsum[wid] = x;
    __syncthreads();
    float off = 0.f;
    for (int w = 0; w < wid; ++w) off += wsum[w];
    const float excl = off + x - s;
    c[tid * 4 + 0] = excl + p0;
    c[tid * 4 + 1] = excl + p1;
    c[tid * 4 + 2] = excl + p2;
    c[tid * 4 + 3] = excl + p3;
}

// ============ scatter: ty->tx map + ones into attn^T ============
__global__ __launch_bounds__(256) void scatter_ones(
    const float* __restrict__ cum, int* __restrict__ tymap, float* __restrict__ out4, int tde)
{
    const int idx = blockIdx.x * 256 + threadIdx.x;   // b*T_EN + tx
    const int b = idx >> 10, tx = idx & 1023;
    const float c1f = cum[idx];
    const float c0f = tx ? cum[idx - 1] : 0.f;
    const int c0 = (int)c0f, c1 = (int)c1f;
    float* o4 = out4 + (size_t)b * tde * T_EN + tx;
    int* mp = tymap + (size_t)b * tde;
    for (int ty = c0; ty < c1; ++ty) {
        mp[ty] = tx;
        o4[(size_t)ty * T_EN] = 1.f;
    }
}

// ============ gather via LDS transpose tile: out3[b,c,ty] = enc[b,tx(ty),c] ============
__global__ __launch_bounds__(256) void gather3(
    const float* __restrict__ enc, const float* __restrict__ cum,
    const int* __restrict__ tymap, float* __restrict__ out3, int tde)
{
    __shared__ float tile[64][65];
    const int b = blockIdx.z, c0 = blockIdx.y * 64, ty0 = blockIdx.x * 64;
    const int lane = threadIdx.x & 63, rg = threadIdx.x >> 6;
    const int mel = (int)cum[(size_t)b * T_EN + T_EN - 1];
#pragma unroll
    for (int p = 0; p < 16; ++p) {
        const int tyl = p * 4 + rg;
        const int ty = ty0 + tyl;
        float v = 0.f;
        if (ty < tde && ty < mel) {
            const int tx = tymap[(size_t)b * tde + ty];
            v = enc[((size_t)(b * T_EN + tx)) * C_INN + c0 + lane];
        }
        tile[tyl][lane] = v;
    }
    __syncthreads();
    const int ty = ty0 + lane;
    if (ty < tde) {
#pragma unroll
        for (int p = 0; p < 16; ++p) {
            const int cl = p * 4 + rg;
            out3[((size_t)(b * C_INN) + c0 + cl) * tde + ty] = tile[lane][cl];
        }
    }
}

extern "C" void kernel_launch(void* const* d_in, const int* in_sizes, int n_in,
                              void* d_out, int out_size, void* d_ws, size_t ws_size,
                              hipStream_t stream)
{
    const float* enc     = (const float*)d_in[0];
    const float* enc_res = (const float*)d_in[1];
    const float* dur     = (const float*)d_in[2];
    const float* c1w     = (const float*)d_in[3];
    const float* c1b     = (const float*)d_in[4];
    const float* g1      = (const float*)d_in[5];
    const float* b1      = (const float*)d_in[6];
    const float* c2w     = (const float*)d_in[7];
    const float* c2b     = (const float*)d_in[8];
    const float* g2      = (const float*)d_in[9];
    const float* b2      = (const float*)d_in[10];
    const float* lw      = (const float*)d_in[11];
    const float* lb      = (const float*)d_in[12];

    const int tde = (out_size - BB * T_EN) / (BB * (2 * T_EN + C_INN));

    float* out1 = (float*)d_out;                                   // [B,T_EN,T_DE] == 0
    float* out2 = out1 + (size_t)BB * T_EN * tde;                  // [B,T_EN]
    float* out3 = out2 + (size_t)BB * T_EN;                        // [B,C_IN,T_DE]
    float* out4 = out3 + (size_t)BB * C_INN * tde;                 // [B,T_DE,T_EN]

    // big transients live in the out1 region (memset after they die)
    char* o1r = (char*)out1;
    unsigned short* xhi = (unsigned short*)o1r;                          // 16.84 MB
    unsigned short* xlo = xhi + (size_t)BB * TPAD * C_INN;               // 16.84 MB
    float* y1 = (float*)(xlo + (size_t)BB * TPAD * C_INN);               // 16.78 MB

    // d_ws layout (~38 MB)
    char* w8 = (char*)d_ws;
    unsigned short* x2hi = (unsigned short*)w8; w8 += (size_t)BB * TPAD * C_H * 2;
    unsigned short* x2lo = (unsigned short*)w8; w8 += (size_t)BB * TPAD * C_H * 2;
    unsigned short* w1hi = (unsigned short*)w8; w8 += (size_t)KSZ * C_H * C_INN * 2;
    unsigned short* w1lo = (unsigned short*)w8; w8 += (size_t)KSZ * C_H * C_INN * 2;
    unsigned short* w2hi = (unsigned short*)w8; w8 += (size_t)KSZ * C_H * C_H * 2;
    unsigned short* w2lo = (unsigned short*)w8; w8 += (size_t)KSZ * C_H * C_H * 2;
    float* y2  = (float*)w8; w8 += (size_t)BB * T_EN * C_H * 4;
    float* cum = (float*)w8; w8 += (size_t)BB * T_EN * 4;
    int* tymap = (int*)w8;

    // conversions
    cvt_x<<<dim3(BB * TPAD * C_INN / 4 / 256), 256, 0, stream>>>(enc_res, xhi, xlo);
    cvt_w<<<dim3(C_H * C_INN / 256), 256, 0, stream>>>(c1w, w1hi, w1lo, C_INN);
    cvt_w<<<dim3(C_H * C_H / 256), 256, 0, stream>>>(c2w, w2hi, w2lo, C_H);

    // conv1 (MFMA) -> y1 ; LN1 -> padded hi/lo
    conv_mfma<C_INN><<<dim3(T_EN / 128, 2, BB), 256, 0, stream>>>(xhi, xlo, w1hi, w1lo, c1b, y1);
    ln1_pad<<<dim3(BB * TPAD / 4), 256, 0, stream>>>(y1, g1, b1, x2hi, x2lo);

    // transients in out1 are dead now: zero-fill alignment outputs
    hipMemsetAsync(out1, 0, (size_t)BB * T_EN * tde * sizeof(float), stream);
    hipMemsetAsync(out4, 0, (size_t)BB * tde * T_EN * sizeof(float), stream);

    // conv2 (MFMA) -> y2 ; fused LN2 + linear head
    conv_mfma<C_H><<<dim3(T_EN / 128, 2, BB), 256, 0, stream>>>(x2hi, x2lo, w2hi, w2lo, c2b, y2);
    ln2_linear<<<dim3(BB * T_EN / 4), 256, 0, stream>>>(y2, g2, b2, lw, lb, dur, out2);

    // alignment path (exact integer durations)
    scan_dur<<<dim3(BB), 256, 0, stream>>>(dur, cum);
    scatter_ones<<<dim3(BB * T_EN / 256), 256, 0, stream>>>(cum, tymap, out4, tde);
    gather3<<<dim3((tde + 63) / 64, C_INN / 64, BB), 256, 0, stream>>>(enc, cum, tymap, out3, tde);
}

// Round 8
// 583.092 us; speedup vs baseline: 1.5786x; 1.0317x over previous
//
#include <hip/hip_runtime.h>
#include <hip/hip_bf16.h>
#include <math.h>

#define BB 16
#define T_EN 1024
#define TPAD 1028
#define C_INN 512
#define C_H 256
#define KSZ 5

typedef __bf16 bf16x8 __attribute__((ext_vector_type(8)));
typedef float  f32x4  __attribute__((ext_vector_type(4)));

__device__ __forceinline__ unsigned short f2bf(float x) {
    __hip_bfloat16 h = __float2bfloat16(x);
    return *reinterpret_cast<unsigned short*>(&h);
}
__device__ __forceinline__ float bf2f(unsigned short u) {
    __hip_bfloat16 h = *reinterpret_cast<__hip_bfloat16*>(&u);
    return __bfloat162float(h);
}
__device__ __forceinline__ void split_bf(float x, unsigned short& hi, unsigned short& lo) {
    unsigned short h = f2bf(x);
    hi = h;
    lo = f2bf(x - bf2f(h));
}

__device__ __forceinline__ void gl_lds16(const void* g, void* l) {
    __builtin_amdgcn_global_load_lds(
        (const __attribute__((address_space(1))) unsigned int*)g,
        (__attribute__((address_space(3))) unsigned int*)l, 16, 0, 0);
}

// ============ MFMA conv-as-GEMM, split-bf16 (hi/lo) ============
// tile 128(M) x 64(N), BK=32, 4 waves (2x2), wave tile 64x32.
// grid = (T_EN/128=8, C_H/64=4, B=16) = 512 blocks = 2 blocks/CU.
// LDS/buffer: Ahi 8K, Alo 8K, Bhi 4K, Blo 4K = 24K; x2 dbuf = 48K -> 3 blocks fit.
// x: padded hi/lo bf16 [B][TPAD][CIN] (rows 0,1,TPAD-2,TPAD-1 zero)
// w: hi/lo bf16 [KSZ][C_H][CIN]  (B^T layout: [n][k])
template<int CIN>
__global__ __launch_bounds__(256) void conv_mfma(
    const unsigned short* __restrict__ xhi, const unsigned short* __restrict__ xlo,
    const unsigned short* __restrict__ whi, const unsigned short* __restrict__ wlo,
    const float* __restrict__ bias, float* __restrict__ y)
{
    constexpr int NS = KSZ * CIN / 32;
    __shared__ char smem[49152];

    const int t0 = blockIdx.x * 128, n0 = blockIdx.y * 64, b = blockIdx.z;
    const int tid = threadIdx.x, lane = tid & 63;
    const int wr = (tid >> 6) >> 1, wc = (tid >> 6) & 1;   // 2x2 waves
    const int l15 = lane & 15, k8 = lane >> 4;

    f32x4 acc[4][2];
#pragma unroll
    for (int i = 0; i < 4; ++i)
#pragma unroll
        for (int j = 0; j < 2; ++j) acc[i][j] = (f32x4){0.f, 0.f, 0.f, 0.f};

    auto stage = [&](int s, int bufi) {
        const int kk = s / (CIN / 32);
        const int ci0 = (s % (CIN / 32)) * 32;
        char* bufA_hi = smem + bufi * 24576;
        char* bufA_lo = bufA_hi + 8192;
        char* bufB_hi = bufA_hi + 16384;
        char* bufB_lo = bufA_hi + 20480;
        const int tp0 = t0 + kk;                      // padded row base
        const int rowA = tid >> 2;                    // 0..63 (+64 for p=1)
        const int k8l = tid & 3;
#pragma unroll
        for (int p = 0; p < 2; ++p) {
            const int row = p * 64 + rowA;            // tile-local 0..127
            const int k8s = k8l ^ ((row ^ (row >> 2)) & 3);     // source pre-swizzle
            const int lb = p * 4096 + (tid & 192) * 16;         // wave-uniform LDS base
            const size_t ga = (size_t)(b * TPAD + tp0 + row) * CIN + ci0 + k8s * 8;
            gl_lds16(xhi + ga, bufA_hi + lb);
            gl_lds16(xlo + ga, bufA_lo + lb);
        }
        {
            const int row = rowA;                     // 0..63
            const int k8s = k8l ^ ((row ^ (row >> 2)) & 3);
            const int lb = (tid & 192) * 16;
            const size_t gb = (size_t)(kk * C_H + n0 + row) * CIN + ci0 + k8s * 8;
            gl_lds16(whi + gb, bufB_hi + lb);
            gl_lds16(wlo + gb, bufB_lo + lb);
        }
    };

    auto compute = [&](int bufi) {
        const char* A_hi = smem + bufi * 24576;
        const char* A_lo = A_hi + 8192;
        const char* B_hi = A_hi + 16384;
        const char* B_lo = A_hi + 20480;
        bf16x8 ah[4], al[4], bh[2], bl[2];
#pragma unroll
        for (int mf = 0; mf < 4; ++mf) {
            const int r = wr * 64 + mf * 16 + l15;
            const int off = r * 64 + ((k8 ^ ((r ^ (r >> 2)) & 3)) * 16);
            ah[mf] = *(const bf16x8*)(A_hi + off);
            al[mf] = *(const bf16x8*)(A_lo + off);
        }
#pragma unroll
        for (int nf = 0; nf < 2; ++nf) {
            const int r = wc * 32 + nf * 16 + l15;
            const int off = r * 64 + ((k8 ^ ((r ^ (r >> 2)) & 3)) * 16);
            bh[nf] = *(const bf16x8*)(B_hi + off);
            bl[nf] = *(const bf16x8*)(B_lo + off);
        }
#pragma unroll
        for (int mf = 0; mf < 4; ++mf)
#pragma unroll
            for (int nf = 0; nf < 2; ++nf)
                acc[mf][nf] = __builtin_amdgcn_mfma_f32_16x16x32_bf16(ah[mf], bh[nf], acc[mf][nf], 0, 0, 0);
#pragma unroll
        for (int mf = 0; mf < 4; ++mf)
#pragma unroll
            for (int nf = 0; nf < 2; ++nf)
                acc[mf][nf] = __builtin_amdgcn_mfma_f32_16x16x32_bf16(ah[mf], bl[nf], acc[mf][nf], 0, 0, 0);
#pragma unroll
        for (int mf = 0; mf < 4; ++mf)
#pragma unroll
            for (int nf = 0; nf < 2; ++nf)
                acc[mf][nf] = __builtin_amdgcn_mfma_f32_16x16x32_bf16(al[mf], bh[nf], acc[mf][nf], 0, 0, 0);
    };

    stage(0, 0);
    __syncthreads();
    for (int s = 0; s < NS; ++s) {
        if (s + 1 < NS) stage(s + 1, (s + 1) & 1);
        compute(s & 1);
        __syncthreads();
    }

    // epilogue: bias + relu, C layout col=lane&15, row=(lane>>4)*4+j
    float bv[2];
#pragma unroll
    for (int nf = 0; nf < 2; ++nf) bv[nf] = bias[n0 + wc * 32 + nf * 16 + l15];
#pragma unroll
    for (int mf = 0; mf < 4; ++mf) {
        const int rbase = t0 + wr * 64 + mf * 16 + k8 * 4;
#pragma unroll
        for (int nf = 0; nf < 2; ++nf) {
            const int col = n0 + wc * 32 + nf * 16 + l15;
            f32x4 v = acc[mf][nf];
#pragma unroll
            for (int j = 0; j < 4; ++j)
                y[((size_t)(b * T_EN) + rbase + j) * C_H + col] = fmaxf(v[j] + bv[nf], 0.f);
        }
    }
}

// ============ fp32 -> padded hi/lo bf16 (encoder_output_res) ============
__global__ __launch_bounds__(256) void cvt_x(
    const float* __restrict__ src, unsigned short* __restrict__ hi, unsigned short* __restrict__ lo)
{
    const size_t i4 = (size_t)blockIdx.x * 256 + threadIdx.x;  // one float4
    const int c4 = (int)(i4 % (C_INN / 4));
    const int r  = (int)((i4 / (C_INN / 4)) % TPAD);
    const int b  = (int)(i4 / ((size_t)(C_INN / 4) * TPAD));
    const size_t dst = ((size_t)(b * TPAD + r)) * C_INN + c4 * 4;
    ushort4 h = {0, 0, 0, 0}, l = {0, 0, 0, 0};
    if (r >= 2 && r < TPAD - 2) {
        float4 v = *(const float4*)(src + ((size_t)(b * T_EN + r - 2)) * C_INN + c4 * 4);
        split_bf(v.x, h.x, l.x); split_bf(v.y, h.y, l.y);
        split_bf(v.z, h.z, l.z); split_bf(v.w, h.w, l.w);
    }
    *(ushort4*)(hi + dst) = h;
    *(ushort4*)(lo + dst) = l;
}

// ============ weights [C_H][CIN][KSZ] fp32 -> [KSZ][C_H][CIN] hi/lo bf16 ============
__global__ __launch_bounds__(256) void cvt_w(
    const float* __restrict__ w, unsigned short* __restrict__ whi, unsigned short* __restrict__ wlo, int CIN)
{
    const int idx = blockIdx.x * 256 + threadIdx.x;   // co*CIN + ci
    const int co = idx / CIN, ci = idx % CIN;
    const float* ps = w + ((size_t)co * CIN + ci) * KSZ;
#pragma unroll
    for (int kk = 0; kk < KSZ; ++kk) {
        unsigned short h, l;
        split_bf(ps[kk], h, l);
        const size_t d = ((size_t)kk * C_H + co) * CIN + ci;
        whi[d] = h; wlo[d] = l;
    }
}

// ============ LN1: fp32 conv1 out -> padded hi/lo bf16 [B][TPAD][C_H] ============
__global__ __launch_bounds__(256) void ln1_pad(
    const float* __restrict__ y1, const float* __restrict__ g, const float* __restrict__ be,
    unsigned short* __restrict__ ohi, unsigned short* __restrict__ olo)
{
    const int rp = blockIdx.x * 4 + (threadIdx.x >> 6);   // over B*TPAD rows
    const int lane = threadIdx.x & 63;
    const int b = rp / TPAD, r = rp % TPAD;
    const size_t dst = (size_t)rp * C_H + lane * 4;
    if (r < 2 || r >= TPAD - 2) {
        ushort4 z = {0, 0, 0, 0};
        *(ushort4*)(ohi + dst) = z;
        *(ushort4*)(olo + dst) = z;
        return;
    }
    float4 v = *(const float4*)(y1 + ((size_t)(b * T_EN + r - 2)) * C_H + lane * 4);
    float s = v.x + v.y + v.z + v.w;
    float q = v.x * v.x + v.y * v.y + v.z * v.z + v.w * v.w;
#pragma unroll
    for (int d = 32; d >= 1; d >>= 1) { s += __shfl_xor(s, d); q += __shfl_xor(q, d); }
    const float mean = s * (1.f / 256.f);
    const float var  = q * (1.f / 256.f) - mean * mean;
    const float inv  = rsqrtf(var + 1e-5f);
    const float4 gg = *(const float4*)(g + lane * 4);
    const float4 bb = *(const float4*)(be + lane * 4);
    float o0 = (v.x - mean) * inv * gg.x + bb.x;
    float o1 = (v.y - mean) * inv * gg.y + bb.y;
    float o2 = (v.z - mean) * inv * gg.z + bb.z;
    float o3 = (v.w - mean) * inv * gg.w + bb.w;
    ushort4 h, l;
    split_bf(o0, h.x, l.x); split_bf(o1, h.y, l.y);
    split_bf(o2, h.z, l.z); split_bf(o3, h.w, l.w);
    *(ushort4*)(ohi + dst) = h;
    *(ushort4*)(olo + dst) = l;
}

// ============ LN2 + linear head + duration mask fused ============
__global__ __launch_bounds__(256) void ln2_linear(
    const float* __restrict__ y2, const float* __restrict__ g, const float* __restrict__ be,
    const float* __restrict__ lw, const float* __restrict__ lb,
    const float* __restrict__ dur, float* __restrict__ out2)
{
    const int row = blockIdx.x * 4 + (threadIdx.x >> 6);
    const int lane = threadIdx.x & 63;
    float4 v = *(const float4*)(y2 + (size_t)row * C_H + lane * 4);
    float s = v.x + v.y + v.z + v.w;
    float q = v.x * v.x + v.y * v.y + v.z * v.z + v.w * v.w;
#pragma unroll
    for (int d = 32; d >= 1; d >>= 1) { s += __shfl_xor(s, d); q += __shfl_xor(q, d); }
    const float mean = s * (1.f / 256.f);
    const float var  = q * (1.f / 256.f) - mean * mean;
    const float inv  = rsqrtf(var + 1e-5f);
    const float4 gg = *(const float4*)(g + lane * 4);
    const float4 bb = *(const float4*)(be + lane * 4);
    const float4 w  = *(const float4*)(lw + lane * 4);
    float t0 = (v.x - mean) * inv * gg.x + bb.x;
    float t1 = (v.y - mean) * inv * gg.y + bb.y;
    float t2 = (v.z - mean) * inv * gg.z + bb.z;
    float t3 = (v.w - mean) * inv * gg.w + bb.w;
    float acc = t0 * w.x + t1 * w.y + t2 * w.z + t3 * w.w;
#pragma unroll
    for (int d = 32; d >= 1; d >>= 1) acc += __shfl_xor(acc, d);
    if (lane == 0) {
        float o = acc + lb[0];
        if (dur[row] == 0.f) o = 0.f;
        out2[row] = o;
    }
}

// ============ per-batch inclusive scan of durations ============
__global__ __launch_bounds__(256) void scan_dur(const float* __restrict__ dur, float* __restrict__ cum)
{
    const int b = blockIdx.x;
    const float* d = dur + (size_t)b * T_EN;
    float* c = cum + (size_t)b * T_EN;
    const int tid = threadIdx.x, lane = tid & 63, wid = tid >> 6;
    float v0 = d[tid * 4 + 0], v1 = d[tid * 4 + 1], v2 = d[tid * 4 + 2], v3 = d[tid * 4 + 3];
    float p0 = v0, p1 = p0 + v1, p2 = p1 + v2, p3 = p2 + v3;
    float s = p3, x = s;
#pragma unroll
    for (int dl = 1; dl < 64; dl <<= 1) {
        float o = __shfl_up(x, dl, 64);
        if (lane >= dl) x += o;
    }
    __shared__ float wsum[4];
    if (lane == 63) wsum[wid] = x;
    __syncthreads();
    float off = 0.f;
    for (int w = 0; w < wid; ++w) off += wsum[w];
    const float excl = off + x - s;
    c[tid * 4 + 0] = excl + p0;
    c[tid * 4 + 1] = excl + p1;
    c[tid * 4 + 2] = excl + p2;
    c[tid * 4 + 3] = excl + p3;
}

// ============ scatter: ty->tx map + ones into attn^T ============
__global__ __launch_bounds__(256) void scatter_ones(
    const float* __restrict__ cum, int* __restrict__ tymap, float* __restrict__ out4, int tde)
{
    const int idx = blockIdx.x * 256 + threadIdx.x;   // b*T_EN + tx
    const int b = idx >> 10, tx = idx & 1023;
    const float c1f = cum[idx];
    const float c0f = tx ? cum[idx - 1] : 0.f;
    const int c0 = (int)c0f, c1 = (int)c1f;
    float* o4 = out4 + (size_t)b * tde * T_EN + tx;
    int* mp = tymap + (size_t)b * tde;
    for (int ty = c0; ty < c1; ++ty) {
        mp[ty] = tx;
        o4[(size_t)ty * T_EN] = 1.f;
    }
}

// ============ gather via LDS transpose tile: out3[b,c,ty] = enc[b,tx(ty),c] ============
__global__ __launch_bounds__(256) void gather3(
    const float* __restrict__ enc, const float* __restrict__ cum,
    const int* __restrict__ tymap, float* __restrict__ out3, int tde)
{
    __shared__ float tile[64][65];
    const int b = blockIdx.z, c0 = blockIdx.y * 64, ty0 = blockIdx.x * 64;
    const int lane = threadIdx.x & 63, rg = threadIdx.x >> 6;
    const int mel = (int)cum[(size_t)b * T_EN + T_EN - 1];
#pragma unroll
    for (int p = 0; p < 16; ++p) {
        const int tyl = p * 4 + rg;
        const int ty = ty0 + tyl;
        float v = 0.f;
        if (ty < tde && ty < mel) {
            const int tx = tymap[(size_t)b * tde + ty];
            v = enc[((size_t)(b * T_EN + tx)) * C_INN + c0 + lane];
        }
        tile[tyl][lane] = v;
    }
    __syncthreads();
    const int ty = ty0 + lane;
    if (ty < tde) {
#pragma unroll
        for (int p = 0; p < 16; ++p) {
            const int cl = p * 4 + rg;
            out3[((size_t)(b * C_INN) + c0 + cl) * tde + ty] = tile[lane][cl];
        }
    }
}

extern "C" void kernel_launch(void* const* d_in, const int* in_sizes, int n_in,
                              void* d_out, int out_size, void* d_ws, size_t ws_size,
                              hipStream_t stream)
{
    const float* enc     = (const float*)d_in[0];
    const float* enc_res = (const float*)d_in[1];
    const float* dur     = (const float*)d_in[2];
    const float* c1w     = (const float*)d_in[3];
    const float* c1b     = (const float*)d_in[4];
    const float* g1      = (const float*)d_in[5];
    const float* b1      = (const float*)d_in[6];
    const float* c2w     = (const float*)d_in[7];
    const float* c2b     = (const float*)d_in[8];
    const float* g2      = (const float*)d_in[9];
    const float* b2      = (const float*)d_in[10];
    const float* lw      = (const float*)d_in[11];
    const float* lb      = (const float*)d_in[12];

    const int tde = (out_size - BB * T_EN) / (BB * (2 * T_EN + C_INN));

    float* out1 = (float*)d_out;                                   // [B,T_EN,T_DE] == 0
    float* out2 = out1 + (size_t)BB * T_EN * tde;                  // [B,T_EN]
    float* out3 = out2 + (size_t)BB * T_EN;                        // [B,C_IN,T_DE]
    float* out4 = out3 + (size_t)BB * C_INN * tde;                 // [B,T_DE,T_EN]

    // big transients live in the out1 region (memset after they die)
    char* o1r = (char*)out1;
    unsigned short* xhi = (unsigned short*)o1r;                          // 16.84 MB
    unsigned short* xlo = xhi + (size_t)BB * TPAD * C_INN;               // 16.84 MB
    float* y1 = (float*)(xlo + (size_t)BB * TPAD * C_INN);               // 16.78 MB

    // d_ws layout (~38 MB)
    char* w8 = (char*)d_ws;
    unsigned short* x2hi = (unsigned short*)w8; w8 += (size_t)BB * TPAD * C_H * 2;
    unsigned short* x2lo = (unsigned short*)w8; w8 += (size_t)BB * TPAD * C_H * 2;
    unsigned short* w1hi = (unsigned short*)w8; w8 += (size_t)KSZ * C_H * C_INN * 2;
    unsigned short* w1lo = (unsigned short*)w8; w8 += (size_t)KSZ * C_H * C_INN * 2;
    unsigned short* w2hi = (unsigned short*)w8; w8 += (size_t)KSZ * C_H * C_H * 2;
    unsigned short* w2lo = (unsigned short*)w8; w8 += (size_t)KSZ * C_H * C_H * 2;
    float* y2  = (float*)w8; w8 += (size_t)BB * T_EN * C_H * 4;
    float* cum = (float*)w8; w8 += (size_t)BB * T_EN * 4;
    int* tymap = (int*)w8;

    // conversions
    cvt_x<<<dim3(BB * TPAD * C_INN / 4 / 256), 256, 0, stream>>>(enc_res, xhi, xlo);
    cvt_w<<<dim3(C_H * C_INN / 256), 256, 0, stream>>>(c1w, w1hi, w1lo, C_INN);
    cvt_w<<<dim3(C_H * C_H / 256), 256, 0, stream>>>(c2w, w2hi, w2lo, C_H);

    // conv1 (MFMA) -> y1 ; LN1 -> padded hi/lo
    conv_mfma<C_INN><<<dim3(T_EN / 128, C_H / 64, BB), 256, 0, stream>>>(xhi, xlo, w1hi, w1lo, c1b, y1);
    ln1_pad<<<dim3(BB * TPAD / 4), 256, 0, stream>>>(y1, g1, b1, x2hi, x2lo);

    // transients in out1 are dead now: zero-fill alignment outputs
    hipMemsetAsync(out1, 0, (size_t)BB * T_EN * tde * sizeof(float), stream);
    hipMemsetAsync(out4, 0, (size_t)BB * tde * T_EN * sizeof(float), stream);

    // conv2 (MFMA) -> y2 ; fused LN2 + linear head
    conv_mfma<C_H><<<dim3(T_EN / 128, C_H / 64, BB), 256, 0, stream>>>(x2hi, x2lo, w2hi, w2lo, c2b, y2);
    ln2_linear<<<dim3(BB * T_EN / 4), 256, 0, stream>>>(y2, g2, b2, lw, lb, dur, out2);

    // alignment path (exact integer durations)
    scan_dur<<<dim3(BB), 256, 0, stream>>>(dur, cum);
    scatter_ones<<<dim3(BB * T_EN / 256), 256, 0, stream>>>(cum, tymap, out4, tde);
    gather3<<<dim3((tde + 63) / 64, C_INN / 64, BB), 256, 0, stream>>>(enc, cum, tymap, out3, tde);
}

// Round 13
// 570.821 us; speedup vs baseline: 1.6125x; 1.0215x over previous
//
#include <hip/hip_runtime.h>
#include <hip/hip_bf16.h>
#include <math.h>

#define BB 16
#define T_EN 1024
#define TPAD 1028
#define C_INN 512
#define C_H 256
#define KSZ 5

typedef __bf16 bf16x8 __attribute__((ext_vector_type(8)));
typedef float  f32x4  __attribute__((ext_vector_type(4)));

__device__ __forceinline__ unsigned short f2bf(float x) {
    __hip_bfloat16 h = __float2bfloat16(x);
    return *reinterpret_cast<unsigned short*>(&h);
}
__device__ __forceinline__ float bf2f(unsigned short u) {
    __hip_bfloat16 h = *reinterpret_cast<__hip_bfloat16*>(&u);
    return __bfloat162float(h);
}
__device__ __forceinline__ void split_bf(float x, unsigned short& hi, unsigned short& lo) {
    unsigned short h = f2bf(x);
    hi = h;
    lo = f2bf(x - bf2f(h));
}

__device__ __forceinline__ void gl_lds16(const void* g, void* l) {
    __builtin_amdgcn_global_load_lds(
        (const __attribute__((address_space(1))) unsigned int*)g,
        (__attribute__((address_space(3))) unsigned int*)l, 16, 0, 0);
}

// ============ MFMA conv-as-GEMM, split-bf16 (hi/lo) ============
// tile 128(M) x 64(N), BK=32, 4 waves (2x2), wave tile 64x32.
// grid = (T_EN/128=8, C_H/64=4, B=16) = 512 blocks = 2 blocks/CU.
// LDS: 24K/buf x2 dbuf = 48K -> 3 blocks/CU by LDS.
// K-loop: counted vmcnt(6) (T4) — prefetch of stage s+1 stays in flight
// across barrier-1; only stage s's 6 loads are drained. __syncthreads here
// (vmcnt(0) drain) was the limiter: every stage paid full load latency.
template<int CIN>
__global__ __launch_bounds__(256) void conv_mfma(
    const unsigned short* __restrict__ xhi, const unsigned short* __restrict__ xlo,
    const unsigned short* __restrict__ whi, const unsigned short* __restrict__ wlo,
    const float* __restrict__ bias, float* __restrict__ y)
{
    constexpr int NS = KSZ * CIN / 32;
    __shared__ char smem[49152];

    const int t0 = blockIdx.x * 128, n0 = blockIdx.y * 64, b = blockIdx.z;
    const int tid = threadIdx.x, lane = tid & 63;
    const int wr = (tid >> 6) >> 1, wc = (tid >> 6) & 1;   // 2x2 waves
    const int l15 = lane & 15, k8 = lane >> 4;

    f32x4 acc[4][2];
#pragma unroll
    for (int i = 0; i < 4; ++i)
#pragma unroll
        for (int j = 0; j < 2; ++j) acc[i][j] = (f32x4){0.f, 0.f, 0.f, 0.f};

    auto stage = [&](int s, int bufi) {
        const int kk = s / (CIN / 32);
        const int ci0 = (s % (CIN / 32)) * 32;
        char* bufA_hi = smem + bufi * 24576;
        char* bufA_lo = bufA_hi + 8192;
        char* bufB_hi = bufA_hi + 16384;
        char* bufB_lo = bufA_hi + 20480;
        const int tp0 = t0 + kk;                      // padded row base
        const int rowA = tid >> 2;                    // 0..63 (+64 for p=1)
        const int k8l = tid & 3;
#pragma unroll
        for (int p = 0; p < 2; ++p) {
            const int row = p * 64 + rowA;            // tile-local 0..127
            const int k8s = k8l ^ ((row ^ (row >> 2)) & 3);     // source pre-swizzle
            const int lb = p * 4096 + (tid & 192) * 16;         // wave-uniform LDS base
            const size_t ga = (size_t)(b * TPAD + tp0 + row) * CIN + ci0 + k8s * 8;
            gl_lds16(xhi + ga, bufA_hi + lb);
            gl_lds16(xlo + ga, bufA_lo + lb);
        }
        {
            const int row = rowA;                     // 0..63
            const int k8s = k8l ^ ((row ^ (row >> 2)) & 3);
            const int lb = (tid & 192) * 16;
            const size_t gb = (size_t)(kk * C_H + n0 + row) * CIN + ci0 + k8s * 8;
            gl_lds16(whi + gb, bufB_hi + lb);
            gl_lds16(wlo + gb, bufB_lo + lb);
        }
    };

    auto compute = [&](int bufi) {
        const char* A_hi = smem + bufi * 24576;
        const char* A_lo = A_hi + 8192;
        const char* B_hi = A_hi + 16384;
        const char* B_lo = A_hi + 20480;
        bf16x8 ah[4], al[4], bh[2], bl[2];
#pragma unroll
        for (int mf = 0; mf < 4; ++mf) {
            const int r = wr * 64 + mf * 16 + l15;
            const int off = r * 64 + ((k8 ^ ((r ^ (r >> 2)) & 3)) * 16);
            ah[mf] = *(const bf16x8*)(A_hi + off);
            al[mf] = *(const bf16x8*)(A_lo + off);
        }
#pragma unroll
        for (int nf = 0; nf < 2; ++nf) {
            const int r = wc * 32 + nf * 16 + l15;
            const int off = r * 64 + ((k8 ^ ((r ^ (r >> 2)) & 3)) * 16);
            bh[nf] = *(const bf16x8*)(B_hi + off);
            bl[nf] = *(const bf16x8*)(B_lo + off);
        }
#pragma unroll
        for (int mf = 0; mf < 4; ++mf)
#pragma unroll
            for (int nf = 0; nf < 2; ++nf)
                acc[mf][nf] = __builtin_amdgcn_mfma_f32_16x16x32_bf16(ah[mf], bh[nf], acc[mf][nf], 0, 0, 0);
#pragma unroll
        for (int mf = 0; mf < 4; ++mf)
#pragma unroll
            for (int nf = 0; nf < 2; ++nf)
                acc[mf][nf] = __builtin_amdgcn_mfma_f32_16x16x32_bf16(ah[mf], bl[nf], acc[mf][nf], 0, 0, 0);
#pragma unroll
        for (int mf = 0; mf < 4; ++mf)
#pragma unroll
            for (int nf = 0; nf < 2; ++nf)
                acc[mf][nf] = __builtin_amdgcn_mfma_f32_16x16x32_bf16(al[mf], bh[nf], acc[mf][nf], 0, 0, 0);
    };

    stage(0, 0);
    for (int s = 0; s < NS; ++s) {
        if (s + 1 < NS) {
            stage(s + 1, (s + 1) & 1);
            // wait only for stage s's 6 loads; s+1's 6 stay in flight (T4)
            asm volatile("s_waitcnt vmcnt(6)" ::: "memory");
        } else {
            asm volatile("s_waitcnt vmcnt(0)" ::: "memory");
        }
        __builtin_amdgcn_s_barrier();
        __builtin_amdgcn_sched_barrier(0);   // rule #18: pin ds_reads after barrier
        compute(s & 1);
        __builtin_amdgcn_s_barrier();        // WAR: buf s reused at stage s+2
    }

    // epilogue: bias + relu, C layout col=lane&15, row=(lane>>4)*4+j
    float bv[2];
#pragma unroll
    for (int nf = 0; nf < 2; ++nf) bv[nf] = bias[n0 + wc * 32 + nf * 16 + l15];
#pragma unroll
    for (int mf = 0; mf < 4; ++mf) {
        const int rbase = t0 + wr * 64 + mf * 16 + k8 * 4;
#pragma unroll
        for (int nf = 0; nf < 2; ++nf) {
            const int col = n0 + wc * 32 + nf * 16 + l15;
            f32x4 v = acc[mf][nf];
#pragma unroll
            for (int j = 0; j < 4; ++j)
                y[((size_t)(b * T_EN) + rbase + j) * C_H + col] = fmaxf(v[j] + bv[nf], 0.f);
        }
    }
}

// ============ fp32 -> padded hi/lo bf16 (encoder_output_res) ============
__global__ __launch_bounds__(256) void cvt_x(
    const float* __restrict__ src, unsigned short* __restrict__ hi, unsigned short* __restrict__ lo)
{
    const size_t i4 = (size_t)blockIdx.x * 256 + threadIdx.x;  // one float4
    const int c4 = (int)(i4 % (C_INN / 4));
    const int r  = (int)((i4 / (C_INN / 4)) % TPAD);
    const int b  = (int)(i4 / ((size_t)(C_INN / 4) * TPAD));
    const size_t dst = ((size_t)(b * TPAD + r)) * C_INN + c4 * 4;
    ushort4 h = {0, 0, 0, 0}, l = {0, 0, 0, 0};
    if (r >= 2 && r < TPAD - 2) {
        float4 v = *(const float4*)(src + ((size_t)(b * T_EN + r - 2)) * C_INN + c4 * 4);
        split_bf(v.x, h.x, l.x); split_bf(v.y, h.y, l.y);
        split_bf(v.z, h.z, l.z); split_bf(v.w, h.w, l.w);
    }
    *(ushort4*)(hi + dst) = h;
    *(ushort4*)(lo + dst) = l;
}

// ============ weights [C_H][CIN][KSZ] fp32 -> [KSZ][C_H][CIN] hi/lo bf16 ============
__global__ __launch_bounds__(256) void cvt_w(
    const float* __restrict__ w, unsigned short* __restrict__ whi, unsigned short* __restrict__ wlo, int CIN)
{
    const int idx = blockIdx.x * 256 + threadIdx.x;   // co*CIN + ci
    const int co = idx / CIN, ci = idx % CIN;
    const float* ps = w + ((size_t)co * CIN + ci) * KSZ;
#pragma unroll
    for (int kk = 0; kk < KSZ; ++kk) {
        unsigned short h, l;
        split_bf(ps[kk], h, l);
        const size_t d = ((size_t)kk * C_H + co) * CIN + ci;
        whi[d] = h; wlo[d] = l;
    }
}

// ============ LN1: fp32 conv1 out -> padded hi/lo bf16 [B][TPAD][C_H] ============
__global__ __launch_bounds__(256) void ln1_pad(
    const float* __restrict__ y1, const float* __restrict__ g, const float* __restrict__ be,
    unsigned short* __restrict__ ohi, unsigned short* __restrict__ olo)
{
    const int rp = blockIdx.x * 4 + (threadIdx.x >> 6);   // over B*TPAD rows
    const int lane = threadIdx.x & 63;
    const int b = rp / TPAD, r = rp % TPAD;
    const size_t dst = (size_t)rp * C_H + lane * 4;
    if (r < 2 || r >= TPAD - 2) {
        ushort4 z = {0, 0, 0, 0};
        *(ushort4*)(ohi + dst) = z;
        *(ushort4*)(olo + dst) = z;
        return;
    }
    float4 v = *(const float4*)(y1 + ((size_t)(b * T_EN + r - 2)) * C_H + lane * 4);
    float s = v.x + v.y + v.z + v.w;
    float q = v.x * v.x + v.y * v.y + v.z * v.z + v.w * v.w;
#pragma unroll
    for (int d = 32; d >= 1; d >>= 1) { s += __shfl_xor(s, d); q += __shfl_xor(q, d); }
    const float mean = s * (1.f / 256.f);
    const float var  = q * (1.f / 256.f) - mean * mean;
    const float inv  = rsqrtf(var + 1e-5f);
    const float4 gg = *(const float4*)(g + lane * 4);
    const float4 bb = *(const float4*)(be + lane * 4);
    float o0 = (v.x - mean) * inv * gg.x + bb.x;
    float o1 = (v.y - mean) * inv * gg.y + bb.y;
    float o2 = (v.z - mean) * inv * gg.z + bb.z;
    float o3 = (v.w - mean) * inv * gg.w + bb.w;
    ushort4 h, l;
    split_bf(o0, h.x, l.x); split_bf(o1, h.y, l.y);
    split_bf(o2, h.z, l.z); split_bf(o3, h.w, l.w);
    *(ushort4*)(ohi + dst) = h;
    *(ushort4*)(olo + dst) = l;
}

// ============ LN2 + linear head + duration mask fused ============
__global__ __launch_bounds__(256) void ln2_linear(
    const float* __restrict__ y2, const float* __restrict__ g, const float* __restrict__ be,
    const float* __restrict__ lw, const float* __restrict__ lb,
    const float* __restrict__ dur, float* __restrict__ out2)
{
    const int row = blockIdx.x * 4 + (threadIdx.x >> 6);
    const int lane = threadIdx.x & 63;
    float4 v = *(const float4*)(y2 + (size_t)row * C_H + lane * 4);
    float s = v.x + v.y + v.z + v.w;
    float q = v.x * v.x + v.y * v.y + v.z * v.z + v.w * v.w;
#pragma unroll
    for (int d = 32; d >= 1; d >>= 1) { s += __shfl_xor(s, d); q += __shfl_xor(q, d); }
    const float mean = s * (1.f / 256.f);
    const float var  = q * (1.f / 256.f) - mean * mean;
    const float inv  = rsqrtf(var + 1e-5f);
    const float4 gg = *(const float4*)(g + lane * 4);
    const float4 bb = *(const float4*)(be + lane * 4);
    const float4 w  = *(const float4*)(lw + lane * 4);
    float t0 = (v.x - mean) * inv * gg.x + bb.x;
    float t1 = (v.y - mean) * inv * gg.y + bb.y;
    float t2 = (v.z - mean) * inv * gg.z + bb.z;
    float t3 = (v.w - mean) * inv * gg.w + bb.w;
    float acc = t0 * w.x + t1 * w.y + t2 * w.z + t3 * w.w;
#pragma unroll
    for (int d = 32; d >= 1; d >>= 1) acc += __shfl_xor(acc, d);
    if (lane == 0) {
        float o = acc + lb[0];
        if (dur[row] == 0.f) o = 0.f;
        out2[row] = o;
    }
}

// ============ per-batch inclusive scan of durations ============
__global__ __launch_bounds__(256) void scan_dur(const float* __restrict__ dur, float* __restrict__ cum)
{
    const int b = blockIdx.x;
    const float* d = dur + (size_t)b * T_EN;
    float* c = cum + (size_t)b * T_EN;
    const int tid = threadIdx.x, lane = tid & 63, wid = tid >> 6;
    float v0 = d[tid * 4 + 0], v1 = d[tid * 4 + 1], v2 = d[tid * 4 + 2], v3 = d[tid * 4 + 3];
    float p0 = v0, p1 = p0 + v1, p2 = p1 + v2, p3 = p2 + v3;
    float s = p3, x = s;
#pragma unroll
    for (int dl = 1; dl < 64; dl <<= 1) {
        float o = __shfl_up(x, dl, 64);
        if (lane >= dl) x += o;
    }
    __shared__ float wsum[4];
    if (lane == 63) wsum[wid] = x;
    __syncthreads();
    float off = 0.f;
    for (int w = 0; w < wid; ++w) off += wsum[w];
    const float excl = off + x - s;
    c[tid * 4 + 0] = excl + p0;
    c[tid * 4 + 1] = excl + p1;
    c[tid * 4 + 2] = excl + p2;
    c[tid * 4 + 3] = excl + p3;
}

// ============ scatter: ty->tx map + ones into attn^T ============
__global__ __launch_bounds__(256) void scatter_ones(
    const float* __restrict__ cum, int* __restrict__ tymap, float* __restrict__ out4, int tde)
{
    const int idx = blockIdx.x * 256 + threadIdx.x;   // b*T_EN + tx
    const int b = idx >> 10, tx = idx & 1023;
    const float c1f = cum[idx];
    const float c0f = tx ? cum[idx - 1] : 0.f;
    const int c0 = (int)c0f, c1 = (int)c1f;
    float* o4 = out4 + (size_t)b * tde * T_EN + tx;
    int* mp = tymap + (size_t)b * tde;
    for (int ty = c0; ty < c1; ++ty) {
        mp[ty] = tx;
        o4[(size_t)ty * T_EN] = 1.f;
    }
}

// ============ gather via LDS transpose tile: out3[b,c,ty] = enc[b,tx(ty),c] ============
__global__ __launch_bounds__(256) void gather3(
    const float* __restrict__ enc, const float* __restrict__ cum,
    const int* __restrict__ tymap, float* __restrict__ out3, int tde)
{
    __shared__ float tile[64][65];
    const int b = blockIdx.z, c0 = blockIdx.y * 64, ty0 = blockIdx.x * 64;
    const int lane = threadIdx.x & 63, rg = threadIdx.x >> 6;
    const int mel = (int)cum[(size_t)b * T_EN + T_EN - 1];
#pragma unroll
    for (int p = 0; p < 16; ++p) {
        const int tyl = p * 4 + rg;
        const int ty = ty0 + tyl;
        float v = 0.f;
        if (ty < tde && ty < mel) {
            const int tx = tymap[(size_t)b * tde + ty];
            v = enc[((size_t)(b * T_EN + tx)) * C_INN + c0 + lane];
        }
        tile[tyl][lane] = v;
    }
    __syncthreads();
    const int ty = ty0 + lane;
    if (ty < tde) {
#pragma unroll
        for (int p = 0; p < 16; ++p) {
            const int cl = p * 4 + rg;
            out3[((size_t)(b * C_INN) + c0 + cl) * tde + ty] = tile[lane][cl];
        }
    }
}

extern "C" void kernel_launch(void* const* d_in, const int* in_sizes, int n_in,
                              void* d_out, int out_size, void* d_ws, size_t ws_size,
                              hipStream_t stream)
{
    const float* enc     = (const float*)d_in[0];
    const float* enc_res = (const float*)d_in[1];
    const float* dur     = (const float*)d_in[2];
    const float* c1w     = (const float*)d_in[3];
    const float* c1b     = (const float*)d_in[4];
    const float* g1      = (const float*)d_in[5];
    const float* b1      = (const float*)d_in[6];
    const float* c2w     = (const float*)d_in[7];
    const float* c2b     = (const float*)d_in[8];
    const float* g2      = (const float*)d_in[9];
    const float* b2      = (const float*)d_in[10];
    const float* lw      = (const float*)d_in[11];
    const float* lb      = (const float*)d_in[12];

    const int tde = (out_size - BB * T_EN) / (BB * (2 * T_EN + C_INN));

    float* out1 = (float*)d_out;                                   // [B,T_EN,T_DE] == 0
    float* out2 = out1 + (size_t)BB * T_EN * tde;                  // [B,T_EN]
    float* out3 = out2 + (size_t)BB * T_EN;                        // [B,C_IN,T_DE]
    float* out4 = out3 + (size_t)BB * C_INN * tde;                 // [B,T_DE,T_EN]

    // big transients live in the out1 region (memset after they die)
    char* o1r = (char*)out1;
    unsigned short* xhi = (unsigned short*)o1r;                          // 16.84 MB
    unsigned short* xlo = xhi + (size_t)BB * TPAD * C_INN;               // 16.84 MB
    float* y1 = (float*)(xlo + (size_t)BB * TPAD * C_INN);               // 16.78 MB

    // d_ws layout (~38 MB)
    char* w8 = (char*)d_ws;
    unsigned short* x2hi = (unsigned short*)w8; w8 += (size_t)BB * TPAD * C_H * 2;
    unsigned short* x2lo = (unsigned short*)w8; w8 += (size_t)BB * TPAD * C_H * 2;
    unsigned short* w1hi = (unsigned short*)w8; w8 += (size_t)KSZ * C_H * C_INN * 2;
    unsigned short* w1lo = (unsigned short*)w8; w8 += (size_t)KSZ * C_H * C_INN * 2;
    unsigned short* w2hi = (unsigned short*)w8; w8 += (size_t)KSZ * C_H * C_H * 2;
    unsigned short* w2lo = (unsigned short*)w8; w8 += (size_t)KSZ * C_H * C_H * 2;
    float* y2  = (float*)w8; w8 += (size_t)BB * T_EN * C_H * 4;
    float* cum = (float*)w8; w8 += (size_t)BB * T_EN * 4;
    int* tymap = (int*)w8;

    // conversions
    cvt_x<<<dim3(BB * TPAD * C_INN / 4 / 256), 256, 0, stream>>>(enc_res, xhi, xlo);
    cvt_w<<<dim3(C_H * C_INN / 256), 256, 0, stream>>>(c1w, w1hi, w1lo, C_INN);
    cvt_w<<<dim3(C_H * C_H / 256), 256, 0, stream>>>(c2w, w2hi, w2lo, C_H);

    // conv1 (MFMA) -> y1 ; LN1 -> padded hi/lo
    conv_mfma<C_INN><<<dim3(T_EN / 128, C_H / 64, BB), 256, 0, stream>>>(xhi, xlo, w1hi, w1lo, c1b, y1);
    ln1_pad<<<dim3(BB * TPAD / 4), 256, 0, stream>>>(y1, g1, b1, x2hi, x2lo);

    // transients in out1 are dead now: zero-fill alignment outputs
    hipMemsetAsync(out1, 0, (size_t)BB * T_EN * tde * sizeof(float), stream);
    hipMemsetAsync(out4, 0, (size_t)BB * tde * T_EN * sizeof(float), stream);

    // conv2 (MFMA) -> y2 ; fused LN2 + linear head
    conv_mfma<C_H><<<dim3(T_EN / 128, C_H / 64, BB), 256, 0, stream>>>(x2hi, x2lo, w2hi, w2lo, c2b, y2);
    ln2_linear<<<dim3(BB * T_EN / 4), 256, 0, stream>>>(y2, g2, b2, lw, lb, dur, out2);

    // alignment path (exact integer durations)
    scan_dur<<<dim3(BB), 256, 0, stream>>>(dur, cum);
    scatter_ones<<<dim3(BB * T_EN / 256), 256, 0, stream>>>(cum, tymap, out4, tde);
    gather3<<<dim3((tde + 63) / 64, C_INN / 64, BB), 256, 0, stream>>>(enc, cum, tymap, out3, tde);
}